// Round 4
// baseline (1108.737 us; speedup 1.0000x reference)
//
#include <hip/hip_runtime.h>
#include <hip/hip_cooperative_groups.h>
#include <math.h>

namespace cg = cooperative_groups;

#define EPSF 1e-10f
#define P_NODES (1 << 20)   // H*W per tree

// Native clang vector types — required by __builtin_nontemporal_*.
typedef float vf4 __attribute__((ext_vector_type(4)));
typedef float vf2 __attribute__((ext_vector_type(2)));

// Packed per-node record: contribution value + parent index (-1 = root).
struct __align__(8) NodePair {
    float v;
    int   par;
};

// ---------------------------------------------------------------------------
// XCD-pinned block decomposition. HW dispatches blockIdx.x round-robin over
// the 8 XCDs (blockIdx.x % 8 == XCD). With nTrees == 4, tree t owns XCDs
// {2t, 2t+1}: its random-walk working set (pairs hop region + out prefix,
// <= 6 MB/tree) stays in 2 private 4 MiB L2s. Perf heuristic only — the
// mapping is bijective, so correctness never depends on XCD assignment.
// Requires gridDim.x % 8 == 0 (all grids here are).
// ---------------------------------------------------------------------------
__device__ __forceinline__ void tree_decomp(int b, int& tree, int& jj)
{
    tree = (b & 7) >> 1;                 // XCD pair -> tree
    jj   = ((b >> 3) << 1) | (b & 1);    // within-tree block index
}

// ---------------------------------------------------------------------------
// K1: contrib = (x[p]-x[par]) * sigmoid(feats(attrs).w + b), packed out.
// attrs tile staged through LDS with float4 (dwordx4) coalesced loads.
// attrs is stream-once -> nontemporal, keep L2 for x-gather + pairs writes.
// ---------------------------------------------------------------------------
__global__ __launch_bounds__(256) void score_kernel(
    const float* __restrict__ x,
    const float* __restrict__ weight,
    const float* __restrict__ bias,
    const float* __restrict__ attrs,
    const int*   __restrict__ parents,
    NodePair*    __restrict__ dst,
    int N)
{
    __shared__ float sA[256 * 15];

    const int t = threadIdx.x;
    int tree, jj;
    tree_decomp(blockIdx.x, tree, jj);
    const int blockBase = (tree << 20) + (jj << 8);
    const int idx = blockBase + t;

    // 256 rows x 15 floats = 960 float4 loads, fully coalesced, 16 B/lane.
    const vf4* ab4 = (const vf4*)(attrs + (size_t)blockBase * 15);
    vf4* sA4 = (vf4*)sA;
#pragma unroll
    for (int k = t; k < 960; k += 256)
        sA4[k] = __builtin_nontemporal_load(&ab4[k]);

    const int n    = tree % N;
    const float* w = weight + n * 17;
    const float  b = bias[n];

    __syncthreads();

    const float* a = &sA[t * 15];

    float acc = b;
    acc += a[0] * w[0];
    acc += a[1] * w[1];
    acc += a[2] * w[2];
    acc += a[3] * w[3];
    acc += a[4] * w[4];

    const float a5 = a[5];
    const float a6 = a[6];
    const float a7 = a[7];

    acc += __logf(fabsf(a6)    + EPSF) * w[5];
    acc += __logf(fabsf(a7)    + EPSF) * w[6];
    acc += __logf(fabsf(a[8])  + EPSF) * w[7];
    acc += __logf(fabsf(a[9])  + EPSF) * w[8];
    acc += __logf(fabsf(a[10]) + EPSF) * w[9];
    acc += __logf(fabsf(a[11]) + EPSF) * w[10];
    acc += __logf(fabsf(a[12]) + EPSF) * w[11];
    acc += __logf(fabsf(a[13]) + EPSF) * w[12];
    acc += __logf(fabsf(a[14]) + EPSF) * w[13];

    const float lshape = __fsqrt_rn(a7) / (__fsqrt_rn(a6) + EPSF);
    acc += lshape * w[14];
    acc += __cosf(a5) * w[15];
    acc += __sinf(a5) * w[16];

    const float score = 1.0f / (1.0f + __expf(-acc));

    const int   p   = idx & (P_NODES - 1);
    const int   par = parents[idx];
    const float xv  = x[idx];

    NodePair r;
    if (par == p) {                       // root (index 0 per generator)
        r.v   = xv * score;
        r.par = -1;
    } else {
        r.v   = (xv - x[(idx - p) + par]) * score;
        r.par = par;
    }
    dst[idx] = r;
}

// ---------------------------------------------------------------------------
// Chain-walk building blocks.
// ---------------------------------------------------------------------------
__device__ __forceinline__ float full_walk(const NodePair* __restrict__ tp, int p)
{
    NodePair r = tp[p];
    float s = r.v;
    int   c = r.par;
    while (c >= 0) {
        NodePair q = tp[c];
        s += q.v;
        c  = q.par;
    }
    return s;
}

// Propagate nodes p in [lo, hi): walk while cur >= lo (indices ~halve per
// hop, E[hops] = 0.386 for ratio-2 chunks), then add final out[cur]
// (cur < lo, already final). Two chains per iteration for MLP; 16B
// coalesced self-loads. last!=0 -> stores never re-read: nontemporal.
__device__ __forceinline__ void chunk_span(
    const NodePair* __restrict__ tp, float* __restrict__ to,
    int tid, int tstride, int lo, int hi, int last)
{
    for (int p0 = lo + (tid << 1); p0 < hi; p0 += (tstride << 1)) {
        float4 r = *(const float4*)(tp + p0);
        float s0 = r.x;  int c0 = __float_as_int(r.y);
        float s1 = r.z;  int c1 = __float_as_int(r.w);

        bool a0 = (c0 >= lo), a1 = (c1 >= lo);
        while (a0 || a1) {
            NodePair q0, q1;
            if (a0) q0 = tp[c0];
            if (a1) q1 = tp[c1];
            if (a0) { s0 += q0.v; c0 = q0.par; a0 = (c0 >= lo); }
            if (a1) { s1 += q1.v; c1 = q1.par; a1 = (c1 >= lo); }
        }
        // c < lo; p >= lo >= 16K can never be the root, so c >= 0.
        s0 += to[c0];
        s1 += to[c1];

        vf2 o; o.x = s0; o.y = s1;
        if (last)
            __builtin_nontemporal_store(o, (vf2*)(to + p0));
        else
            *(vf2*)(to + p0) = o;
    }
}

// ---------------------------------------------------------------------------
// K2 (cooperative): ALL chain phases in one kernel. grid.sync() between
// phases keeps pairs/out L2-resident across phase boundaries (multi-kernel
// version loses dirty L2 lines to the end-of-kernel writeback). Ratio-2
// chunking: each node in [lo,2lo) averages 0.386 hops + 1 out-read
// (~1.49M random reads/tree vs 2.08M for the coarse 4-phase split).
// 1024 blocks x 256 = 4 blocks/CU — co-residency guaranteed at any
// plausible VGPR count. nTrees == 4 assumed (guarded at launch site).
// ---------------------------------------------------------------------------
#define CHAIN_BLOCKS 1024

__global__ __launch_bounds__(256) void chain_all_kernel(
    const NodePair* __restrict__ pairs,
    float*          __restrict__ out)
{
    cg::grid_group grid = cg::this_grid();

    int tree, jj;
    tree_decomp(blockIdx.x, tree, jj);
    const int tpt  = (CHAIN_BLOCKS / 4) * 256;   // threads per tree = 65536
    const int tid  = (jj << 8) + threadIdx.x;
    const NodePair* tp = pairs + (tree << 20);
    float*          to = out   + (tree << 20);

    // Phase F: exact full walks [0, 16K). Hop region 128 KB/tree, L2-hot.
    for (int p = tid; p < (16 << 10); p += tpt)
        to[p] = full_walk(tp, p);
    grid.sync();

    chunk_span(tp, to, tid, tpt,  16 << 10,   32 << 10, 0); grid.sync();
    chunk_span(tp, to, tid, tpt,  32 << 10,   64 << 10, 0); grid.sync();
    chunk_span(tp, to, tid, tpt,  64 << 10,  128 << 10, 0); grid.sync();
    chunk_span(tp, to, tid, tpt, 128 << 10,  256 << 10, 0); grid.sync();
    chunk_span(tp, to, tid, tpt, 256 << 10,  512 << 10, 0); grid.sync();
    chunk_span(tp, to, tid, tpt, 512 << 10, 1024 << 10, 1);
}

// ---------------------------------------------------------------------------
// Fallback path (used only if cooperative launch is unavailable): the
// proven round-2 multi-kernel scheme.
// ---------------------------------------------------------------------------
__global__ __launch_bounds__(256) void frontier_kernel(
    const NodePair* __restrict__ pairs,
    float*          __restrict__ out)
{
    int tree, jj;
    tree_decomp(blockIdx.x, tree, jj);
    const int p    = (jj << 8) + threadIdx.x;     // < 64K
    const int base = tree << 20;
    out[base + p] = full_walk(pairs + base, p);
}

__global__ __launch_bounds__(256) void chunk_kernel(
    const NodePair* __restrict__ pairs,
    float*          __restrict__ out,
    int lo, int last)
{
    int tree, jj;
    tree_decomp(blockIdx.x, tree, jj);
    const int p0   = lo + ((((jj << 8) + threadIdx.x)) << 1);
    const int base = tree << 20;
    const NodePair* tp = pairs + base;
    float*          to = out + base;

    float4 r = *(const float4*)(tp + p0);
    float s0 = r.x;  int c0 = __float_as_int(r.y);
    float s1 = r.z;  int c1 = __float_as_int(r.w);

    bool a0 = (c0 >= lo), a1 = (c1 >= lo);
    while (a0 || a1) {
        NodePair q0, q1;
        if (a0) q0 = tp[c0];
        if (a1) q1 = tp[c1];
        if (a0) { s0 += q0.v; c0 = q0.par; a0 = (c0 >= lo); }
        if (a1) { s1 += q1.v; c1 = q1.par; a1 = (c1 >= lo); }
    }
    // c < lo here; p >= lo >= 64K can never be the root, so c >= 0.
    s0 += to[c0];
    s1 += to[c1];

    vf2 o; o.x = s0; o.y = s1;
    if (last)
        __builtin_nontemporal_store(o, (vf2*)(to + p0));
    else
        *(vf2*)(to + p0) = o;
}

extern "C" void kernel_launch(void* const* d_in, const int* in_sizes, int n_in,
                              void* d_out, int out_size, void* d_ws, size_t ws_size,
                              hipStream_t stream)
{
    const float* x       = (const float*)d_in[0];
    const float* weight  = (const float*)d_in[1];
    const float* bias    = (const float*)d_in[2];
    const float* attrs   = (const float*)d_in[3];
    const int*   parents = (const int*)d_in[4];
    float*       out     = (float*)d_out;

    const int total  = in_sizes[0];           // B*N*P = 4194304
    const int N      = in_sizes[1] / 17;      // weight is (N,17,1)
    const int nTrees = total >> 20;           // 4

    NodePair* pairs = (NodePair*)d_ws;        // 32 MB

    const int block = 256;

    // K1: score + packed contrib/parent. 16384 blocks (mult. of 8, pinned).
    score_kernel<<<total / block, block, 0, stream>>>(x, weight, bias, attrs,
                                                      parents, pairs, N);

    // K2: all chain phases, one cooperative kernel.
    bool coop_ok = false;
    if (nTrees == 4) {
        void* args[2] = { (void*)&pairs, (void*)&out };
        hipError_t e = hipLaunchCooperativeKernel((void*)chain_all_kernel,
                                                  dim3(CHAIN_BLOCKS), dim3(block),
                                                  args, 0, stream);
        coop_ok = (e == hipSuccess);
    }

    if (!coop_ok) {
        // Round-2 fallback: frontier [0,64K) + coarse chunks.
        frontier_kernel<<<(65536 / block) * nTrees, block, 0, stream>>>(pairs, out);
        const int bounds[4] = { 65536, 262144, 524288, 1048576 };
        for (int i = 0; i < 3; ++i) {
            int lo = bounds[i], hi = bounds[i + 1];
            int g  = ((hi - lo) / (2 * block)) * nTrees;
            chunk_kernel<<<g, block, 0, stream>>>(pairs, out, lo, i == 2);
        }
    }
}

// Round 5
// 416.492 us; speedup vs baseline: 2.6621x; 2.6621x over previous
//
#include <hip/hip_runtime.h>
#include <math.h>

#define EPSF 1e-10f
#define P_NODES (1 << 20)   // H*W per tree
#define T_F  16384          // full-walk frontier bound
#define T_C0 65536          // chunk boundaries
#define T_C1 262144

// Native clang vector types — required by __builtin_nontemporal_*.
typedef float vf4 __attribute__((ext_vector_type(4)));
typedef float vf2 __attribute__((ext_vector_type(2)));

// Packed per-node record: contribution value + parent index (-1 = root).
struct __align__(8) NodePair {
    float v;
    int   par;
};

// ---------------------------------------------------------------------------
// XCD-pinned block decomposition. HW dispatches blockIdx.x round-robin over
// the 8 XCDs (blockIdx.x % 8 == XCD). With nTrees == 4, tree t owns XCDs
// {2t, 2t+1}: its random-walk working set (pairs hop region + out prefix)
// stays in 2 private 4 MiB L2s. Perf heuristic only — mapping is bijective,
// so correctness never depends on XCD assignment.
// Requires gridDim.x % 8 == 0 (all grids here are).
// ---------------------------------------------------------------------------
__device__ __forceinline__ void tree_decomp(int b, int& tree, int& jj)
{
    tree = (b & 7) >> 1;                 // XCD pair -> tree
    jj   = ((b >> 3) << 1) | (b & 1);    // within-tree block index
}

// ---------------------------------------------------------------------------
// K1: contrib = (x[p]-x[par]) * sigmoid(feats(attrs).w + b), packed out.
// attrs tile staged through LDS with float4 (dwordx4) coalesced loads.
// attrs is stream-once -> nontemporal, keep L2 for x-gather + pairs writes.
// ---------------------------------------------------------------------------
__global__ __launch_bounds__(256) void score_kernel(
    const float* __restrict__ x,
    const float* __restrict__ weight,
    const float* __restrict__ bias,
    const float* __restrict__ attrs,
    const int*   __restrict__ parents,
    NodePair*    __restrict__ dst,
    int N)
{
    __shared__ float sA[256 * 15];

    const int t = threadIdx.x;
    int tree, jj;
    tree_decomp(blockIdx.x, tree, jj);
    const int blockBase = (tree << 20) + (jj << 8);
    const int idx = blockBase + t;

    // 256 rows x 15 floats = 960 float4 loads, fully coalesced, 16 B/lane.
    const vf4* ab4 = (const vf4*)(attrs + (size_t)blockBase * 15);
    vf4* sA4 = (vf4*)sA;
#pragma unroll
    for (int k = t; k < 960; k += 256)
        sA4[k] = __builtin_nontemporal_load(&ab4[k]);

    const int n    = tree % N;
    const float* w = weight + n * 17;
    const float  b = bias[n];

    __syncthreads();

    const float* a = &sA[t * 15];

    float acc = b;
    acc += a[0] * w[0];
    acc += a[1] * w[1];
    acc += a[2] * w[2];
    acc += a[3] * w[3];
    acc += a[4] * w[4];

    const float a5 = a[5];
    const float a6 = a[6];
    const float a7 = a[7];

    acc += __logf(fabsf(a6)    + EPSF) * w[5];
    acc += __logf(fabsf(a7)    + EPSF) * w[6];
    acc += __logf(fabsf(a[8])  + EPSF) * w[7];
    acc += __logf(fabsf(a[9])  + EPSF) * w[8];
    acc += __logf(fabsf(a[10]) + EPSF) * w[9];
    acc += __logf(fabsf(a[11]) + EPSF) * w[10];
    acc += __logf(fabsf(a[12]) + EPSF) * w[11];
    acc += __logf(fabsf(a[13]) + EPSF) * w[12];
    acc += __logf(fabsf(a[14]) + EPSF) * w[13];

    const float lshape = __fsqrt_rn(a7) / (__fsqrt_rn(a6) + EPSF);
    acc += lshape * w[14];
    acc += __cosf(a5) * w[15];
    acc += __sinf(a5) * w[16];

    const float score = 1.0f / (1.0f + __expf(-acc));

    const int   p   = idx & (P_NODES - 1);
    const int   par = parents[idx];
    const float xv  = x[idx];

    NodePair r;
    if (par == p) {                       // root (index 0 per generator)
        r.v   = xv * score;
        r.par = -1;
    } else {
        r.v   = (xv - x[(idx - p) + par]) * score;
        r.par = par;
    }
    dst[idx] = r;
}

// ---------------------------------------------------------------------------
// K2: frontier — exact root-to-node path sums for p < T_F, written DIRECTLY
// into out (final values). Hop region 128 KB/tree, L2-hot on the tree's
// pinned XCD pair. 1 chain/thread, 64K concurrent chains.
// ---------------------------------------------------------------------------
__global__ __launch_bounds__(256) void frontier_kernel(
    const NodePair* __restrict__ pairs,
    float*          __restrict__ out)
{
    int tree, jj;
    tree_decomp(blockIdx.x, tree, jj);
    const int p    = (jj << 8) + threadIdx.x;     // < T_F
    const int base = tree << 20;
    const NodePair* tp = pairs + base;

    NodePair r = tp[p];
    float s = r.v;
    int   c = r.par;
    while (c >= 0) {
        NodePair q = tp[c];
        s += q.v;
        c  = q.par;
    }
    out[base + p] = s;
}

// ---------------------------------------------------------------------------
// K3..K5: chunk propagation, 8 independent chains per thread for MLP.
// Each block owns a 2048-node span at lo + jj*2048; thread t owns nodes
// S+2t, S+2t+1, S+2t+512, ... (4 coalesced float4 self-loads). Walk all 8
// chains interleaved (8 outstanding random loads) while cur >= lo (E[hops]
// = 0.85 for ratio-4 chunks), then add final out[cur] (cur < lo, uniform
// over [0,lo), L2-pinned). last!=0 -> stores never re-read: nontemporal.
// All scalar state: explicit unroll, no runtime-indexed arrays (rule #20).
// ---------------------------------------------------------------------------
__global__ __launch_bounds__(256) void chunk8_kernel(
    const NodePair* __restrict__ pairs,
    float*          __restrict__ out,
    int lo, int last)
{
    int tree, jj;
    tree_decomp(blockIdx.x, tree, jj);
    const int base = tree << 20;
    const NodePair* tp = pairs + base;
    float*          to = out + base;
    const int S = lo + jj * 2048 + (threadIdx.x << 1);

    float4 r0 = *(const float4*)(tp + S);
    float4 r1 = *(const float4*)(tp + S + 512);
    float4 r2 = *(const float4*)(tp + S + 1024);
    float4 r3 = *(const float4*)(tp + S + 1536);

    float s0 = r0.x; int c0 = __float_as_int(r0.y);
    float s1 = r0.z; int c1 = __float_as_int(r0.w);
    float s2 = r1.x; int c2 = __float_as_int(r1.y);
    float s3 = r1.z; int c3 = __float_as_int(r1.w);
    float s4 = r2.x; int c4 = __float_as_int(r2.y);
    float s5 = r2.z; int c5 = __float_as_int(r2.w);
    float s6 = r3.x; int c6 = __float_as_int(r3.y);
    float s7 = r3.z; int c7 = __float_as_int(r3.w);

    bool a0 = (c0 >= lo), a1 = (c1 >= lo), a2 = (c2 >= lo), a3 = (c3 >= lo);
    bool a4 = (c4 >= lo), a5 = (c5 >= lo), a6 = (c6 >= lo), a7 = (c7 >= lo);

    while (a0 | a1 | a2 | a3 | a4 | a5 | a6 | a7) {
        NodePair q0, q1, q2, q3, q4, q5, q6, q7;
        if (a0) q0 = tp[c0];
        if (a1) q1 = tp[c1];
        if (a2) q2 = tp[c2];
        if (a3) q3 = tp[c3];
        if (a4) q4 = tp[c4];
        if (a5) q5 = tp[c5];
        if (a6) q6 = tp[c6];
        if (a7) q7 = tp[c7];
        if (a0) { s0 += q0.v; c0 = q0.par; a0 = (c0 >= lo); }
        if (a1) { s1 += q1.v; c1 = q1.par; a1 = (c1 >= lo); }
        if (a2) { s2 += q2.v; c2 = q2.par; a2 = (c2 >= lo); }
        if (a3) { s3 += q3.v; c3 = q3.par; a3 = (c3 >= lo); }
        if (a4) { s4 += q4.v; c4 = q4.par; a4 = (c4 >= lo); }
        if (a5) { s5 += q5.v; c5 = q5.par; a5 = (c5 >= lo); }
        if (a6) { s6 += q6.v; c6 = q6.par; a6 = (c6 >= lo); }
        if (a7) { s7 += q7.v; c7 = q7.par; a7 = (c7 >= lo); }
    }

    // c < lo here; p >= lo >= 16K can never be the root, so c >= 0.
    // 8 independent final gathers issued back-to-back.
    float o0 = to[c0], o1 = to[c1], o2 = to[c2], o3 = to[c3];
    float o4 = to[c4], o5 = to[c5], o6 = to[c6], o7 = to[c7];
    s0 += o0; s1 += o1; s2 += o2; s3 += o3;
    s4 += o4; s5 += o5; s6 += o6; s7 += o7;

    vf2 w0; w0.x = s0; w0.y = s1;
    vf2 w1; w1.x = s2; w1.y = s3;
    vf2 w2; w2.x = s4; w2.y = s5;
    vf2 w3; w3.x = s6; w3.y = s7;
    if (last) {
        __builtin_nontemporal_store(w0, (vf2*)(to + S));
        __builtin_nontemporal_store(w1, (vf2*)(to + S + 512));
        __builtin_nontemporal_store(w2, (vf2*)(to + S + 1024));
        __builtin_nontemporal_store(w3, (vf2*)(to + S + 1536));
    } else {
        *(vf2*)(to + S)        = w0;
        *(vf2*)(to + S + 512)  = w1;
        *(vf2*)(to + S + 1024) = w2;
        *(vf2*)(to + S + 1536) = w3;
    }
}

extern "C" void kernel_launch(void* const* d_in, const int* in_sizes, int n_in,
                              void* d_out, int out_size, void* d_ws, size_t ws_size,
                              hipStream_t stream)
{
    const float* x       = (const float*)d_in[0];
    const float* weight  = (const float*)d_in[1];
    const float* bias    = (const float*)d_in[2];
    const float* attrs   = (const float*)d_in[3];
    const int*   parents = (const int*)d_in[4];
    float*       out     = (float*)d_out;

    const int total  = in_sizes[0];           // B*N*P = 4194304
    const int N      = in_sizes[1] / 17;      // weight is (N,17,1)
    const int nTrees = total >> 20;           // 4

    NodePair* pairs = (NodePair*)d_ws;        // 32 MB

    const int block = 256;

    // K1: score + packed contrib/parent. 16384 blocks (mult of 8, pinned).
    score_kernel<<<total / block, block, 0, stream>>>(x, weight, bias, attrs,
                                                      parents, pairs, N);

    // K2: full walks [0,16K). 64 blocks/tree * 4 = 256.
    frontier_kernel<<<(T_F / block) * nTrees, block, 0, stream>>>(pairs, out);

    // K3: [16K,64K), lo=16K. 48K nodes/tree / 2048 = 24 blocks/tree -> 96.
    chunk8_kernel<<<((T_C0 - T_F) / 2048) * nTrees, block, 0, stream>>>(
        pairs, out, T_F, 0);

    // K4: [64K,256K), lo=64K. 96 blocks/tree -> 384.
    chunk8_kernel<<<((T_C1 - T_C0) / 2048) * nTrees, block, 0, stream>>>(
        pairs, out, T_C0, 0);

    // K5: [256K,1M), lo=256K. 384 blocks/tree -> 1536, terminal stores NT.
    chunk8_kernel<<<((P_NODES - T_C1) / 2048) * nTrees, block, 0, stream>>>(
        pairs, out, T_C1, 1);
}